// Round 16
// baseline (413.902 us; speedup 1.0000x reference)
//
#include <hip/hip_runtime.h>

#define TSTEPS 48
#define OUT_STEPS 24
#define L2E 1.44269504088896340736f
#define ECLAMP 30.0f

typedef short bf16x8 __attribute__((ext_vector_type(8)));
typedef float f32x16 __attribute__((ext_vector_type(16)));
typedef unsigned int u32x4 __attribute__((ext_vector_type(4)));

// RNE bf16 hi + truncated-residual lo (weights; off hot path).
__device__ __forceinline__ void bf_split_rne(float f, short& hi, short& lo) {
    unsigned u = __builtin_bit_cast(unsigned, f);
    unsigned r = u + 0x7FFFu + ((u >> 16) & 1u);
    unsigned short hb = (unsigned short)(r >> 16);
    float hif = __builtin_bit_cast(float, (unsigned)hb << 16);
    float lof = f - hif;
    unsigned short lb = (unsigned short)(__builtin_bit_cast(unsigned, lof) >> 16);
    hi = (short)hb; lo = (short)lb;
}

// Truncation split packed into one dword: low16 = hi-bf16, high16 = lo-bf16.
__device__ __forceinline__ unsigned split_pack(float f) {
    unsigned u = __builtin_bit_cast(unsigned, f);
    float hif = __builtin_bit_cast(float, u & 0xFFFF0000u);
    float lof = f - hif;
    unsigned lo = __builtin_bit_cast(unsigned, lof);
    return (u >> 16) | (lo & 0xFFFF0000u);
}

// Gate pre-scale for exp2: i,f,o -> -log2e; g (gate 2) -> -2*log2e.
__device__ __forceinline__ float gate_scale(int g) {
    return (g == 2) ? (-2.0f * L2E) : (-L2E);
}

// U-frag LDS slot for the ACTIVE cell only: (g*2+c)*2+hl, addr (slot*64+lane)*16B.
__device__ __forceinline__ int uslot(int g, int c, int hl) {
    return (g * 2 + c) * 2 + hl;
}

// Stage one cell's weights into LDS. Wave w stages gate g=w (all 4 waves work).
__device__ __forceinline__ void stage_cell(const float* __restrict__ Uks,
                                           const float* __restrict__ Wks,
                                           const float* __restrict__ bvs,
                                           short* __restrict__ uflds,
                                           short* __restrict__ a4lds,
                                           int g, int lane, int m, int H) {
    const float s = gate_scale(g);
#pragma unroll
    for (int c = 0; c < 2; ++c) {
        bf16x8 ah, al;
#pragma unroll
        for (int j = 0; j < 8; ++j) {
            const int uin = 16 * c + 4 * H + (j & 3) + 8 * (j >> 2);
            float wt = Uks[uin * 128 + g * 32 + m] * s;
            short hb, lb; bf_split_rne(wt, hb, lb);
            ah[j] = hb; al[j] = lb;
        }
        *(bf16x8*)(uflds + (uslot(g, c, 0) * 64 + lane) * 8) = ah;
        *(bf16x8*)(uflds + (uslot(g, c, 1) * 64 + lane) * 8) = al;
    }
    // A4: [wk_hi, wk_hi, wk_lo, b_hi, b_lo, 0,0,0] on H==0 lanes, else 0.
    short whi, wlo, bhi, blo;
    bf_split_rne(Wks[g * 32 + m] * s, whi, wlo);
    bf_split_rne(bvs[g * 32 + m] * s, bhi, blo);
    bf16x8 a = {whi, whi, wlo, bhi, blo, 0, 0, 0};
    u32x4 z4 = {0u, 0u, 0u, 0u};
    if (H != 0) a = __builtin_bit_cast(bf16x8, z4);
    *(bf16x8*)(a4lds + (g * 64 + lane) * 8) = a;
}

// One LSTM step for 32 batch rows. h enters/exits as two K-half B-frags
// (identity repack — R12-verified). U-frags + A4 read from LDS each step.
// Activation math VERBATIM from the verified scalar form (absmax 4.88e-4).
template <bool NEED_P>
__device__ __forceinline__ float lstm_step32(unsigned xpack,
    const short* __restrict__ uflds, const short* __restrict__ a4lds,
    bf16x8& B0h, bf16x8& B0l, bf16x8& B1h, bf16x8& B1l,
    float* cs, const float* __restrict__ wdp,  // &wdlds[H][0] (broadcast)
    int lane, int H) {
    // B4 on H==0 lanes: [x_hi, x_lo, x_hi, 1, 1, 0,0,0].
    unsigned w0 = xpack;
    unsigned w1 = (xpack & 0xFFFFu) | 0x3F800000u;
    unsigned w2 = 0x00003F80u;
    if (H != 0) { w0 = 0u; w1 = 0u; w2 = 0u; }
    u32x4 b4u = {w0, w1, w2, 0u};
    const bf16x8 B4 = __builtin_bit_cast(bf16x8, b4u);
    const f32x16 zero16 = {0,0,0,0,0,0,0,0,0,0,0,0,0,0,0,0};

    f32x16 acc[4];
#pragma unroll
    for (int g = 0; g < 4; ++g) {
        const bf16x8 A4g = *(const bf16x8*)(a4lds + (g * 64 + lane) * 8);
        const bf16x8 Ah0 = *(const bf16x8*)(uflds + (uslot(g, 0, 0) * 64 + lane) * 8);
        const bf16x8 Al0 = *(const bf16x8*)(uflds + (uslot(g, 0, 1) * 64 + lane) * 8);
        const bf16x8 Ah1 = *(const bf16x8*)(uflds + (uslot(g, 1, 0) * 64 + lane) * 8);
        const bf16x8 Al1 = *(const bf16x8*)(uflds + (uslot(g, 1, 1) * 64 + lane) * 8);
        f32x16 a = __builtin_amdgcn_mfma_f32_32x32x16_bf16(A4g, B4, zero16, 0, 0, 0);
        a = __builtin_amdgcn_mfma_f32_32x32x16_bf16(Al0, B0h, a, 0, 0, 0);
        a = __builtin_amdgcn_mfma_f32_32x32x16_bf16(Ah0, B0l, a, 0, 0, 0);
        a = __builtin_amdgcn_mfma_f32_32x32x16_bf16(Ah0, B0h, a, 0, 0, 0);
        a = __builtin_amdgcn_mfma_f32_32x32x16_bf16(Al1, B1h, a, 0, 0, 0);
        a = __builtin_amdgcn_mfma_f32_32x32x16_bf16(Ah1, B1l, a, 0, 0, 0);
        a = __builtin_amdgcn_mfma_f32_32x32x16_bf16(Ah1, B1h, a, 0, 0, 0);
        acc[g] = a;
    }

    float pp = 0.0f;
    bf16x8 n0h, n0l, n1h, n1l;
#pragma unroll
    for (int r = 0; r < 16; ++r) {
        float ei = __builtin_amdgcn_exp2f(acc[0][r]);
        float ef = __builtin_amdgcn_exp2f(acc[1][r]);
        float eg = __builtin_amdgcn_exp2f(__builtin_fminf(acc[2][r], ECLAMP));
        float eo = __builtin_amdgcn_exp2f(acc[3][r]);
        float di = 1.0f + ei, df = 1.0f + ef, dg = 1.0f + eg, do_ = 1.0f + eo;
        float ngs = __builtin_fmaf(eg, 2.0f * L2E, -2.0f * L2E);  // -2L2E*(1-eg)
        float t1 = di * dg;
        float t2 = cs[r] * t1;
        float num = __builtin_fmaf(ngs, df, t2);
        float cn = num * __builtin_amdgcn_rcpf(df * t1);          // scaled c'
        cs[r] = cn;
        float ec = __builtin_amdgcn_exp2f(__builtin_fminf(cn, ECLAMP)); // e^-2c
        float h = (1.0f - ec) * __builtin_amdgcn_rcpf(do_ * (1.0f + ec)); // o*tanh(c)
        if constexpr (NEED_P) pp = __builtin_fmaf(h, wdp[r], pp); // LDS broadcast
        unsigned u = __builtin_bit_cast(unsigned, h);
        float hif = __builtin_bit_cast(float, u & 0xFFFF0000u);
        float lof = h - hif;
        short hb = (short)(u >> 16);
        short lb = (short)(__builtin_bit_cast(unsigned, lof) >> 16);
        if (r < 8) { n0h[r] = hb; n0l[r] = lb; }
        else       { n1h[r - 8] = hb; n1l[r - 8] = lb; }
    }
    B0h = n0h; B0l = n0l; B1h = n1h; B1l = n1l;
    return pp;
}

// (256,4): total reg cap 128 (demand ~136 -> compiler shaves ~8 via remat).
// LDS 20.6 KB -> 4 blocks/CU; grid 1024 = exactly 4 blocks/CU (no quantization
// tail, unlike R15's 3-resident 768+256 split). 4 waves/SIMD fills the 32%
// VALU idle from serial MFMA->act alternation at 2 waves.
__global__ __launch_bounds__(256, 4) void lstm_feedback_mfma14(
    const float* __restrict__ inputs,  // [B, 48]
    const float* __restrict__ Wk_w, const float* __restrict__ Uk_w, const float* __restrict__ b_w,
    const float* __restrict__ Wk_d, const float* __restrict__ Uk_d, const float* __restrict__ b_d,
    const float* __restrict__ Wd, const float* __restrict__ bd,
    float* __restrict__ out,           // [B, 24]
    int B) {
    const int tid = threadIdx.x;       // 4 waves x 32 batch = 128 batch/block
    const int w = tid >> 6;
    const int lane = tid & 63;
    const int m = lane & 31;           // batch column within wave / out-unit row
    const int H = lane >> 5;
    const int mblk = blockIdx.x * 128;
    const long row = (long)(mblk + w * 32 + m);

    __shared__ __align__(16) short uflds[16 * 64 * 8];  // 16 KB: ACTIVE cell U-frags
    __shared__ __align__(16) short a4lds[4 * 64 * 8];   // 4 KB: ACTIVE cell A4
    __shared__ float wdlds[2][16];                      // Wd in D-reg order

    // Stage warmup cell (wave w handles gate w).
    stage_cell(Uk_w, Wk_w, b_w, uflds, a4lds, w, lane, m, H);
    // Wd in D-layout order: unit of D reg r is (r&3) + 8*(r>>2) + 4H.
    if (tid < 32) {
        const int r = tid & 15, Hh = tid >> 4;
        wdlds[Hh][r] = Wd[(r & 3) + 8 * (r >> 2) + 4 * Hh];
    }

    u32x4 z4 = {0u, 0u, 0u, 0u};
    bf16x8 B0h = __builtin_bit_cast(bf16x8, z4), B0l = B0h, B1h = B0h, B1l = B0h;
    float cs[16];
#pragma unroll
    for (int r = 0; r < 16; ++r) cs[r] = 0.0f;

    __syncthreads();  // uflds + a4lds + wdlds visible

    const float* __restrict__ wdp = &wdlds[H][0];

    // ---- warmup: per-lane x from global (L2-resident), one-step prefetch ----
    float xc = inputs[row * TSTEPS + 0];
    for (int t = 0; t < TSTEPS - 1; ++t) {
        float xn = inputs[row * TSTEPS + t + 1];  // issued before the step body
        asm volatile("" ::: "memory");  // keep LDS frag reads in-loop (anti-LICM)
        lstm_step32<false>(split_pack(xc), uflds, a4lds,
                           B0h, B0l, B1h, B1l, cs, wdp, lane, H);
        xc = xn;
    }

    const float bdv = bd[0];

    // ---- last warmup step with pred fold; single-shuffle reduce ----
    asm volatile("" ::: "memory");
    float p = lstm_step32<true>(split_pack(xc), uflds, a4lds,
                                B0h, B0l, B1h, B1l, cs, wdp, lane, H);
    p += __shfl_xor(p, 32);
    p += bdv;                          // both H lanes of batch m hold pred(batch m)
    if (H == 0) out[row * OUT_STEPS + 0] = p;

    // ---- restage with decode cell (one barrier each side) ----
    __syncthreads();
    stage_cell(Uk_d, Wk_d, b_d, uflds, a4lds, w, lane, m, H);
    __syncthreads();

    for (int s = 1; s < OUT_STEPS; ++s) {
        asm volatile("" ::: "memory");
        p = lstm_step32<true>(split_pack(p), uflds, a4lds,
                              B0h, B0l, B1h, B1l, cs, wdp, lane, H);
        p += __shfl_xor(p, 32);
        p += bdv;
        if (H == 0) out[row * OUT_STEPS + s] = p;
    }
}

extern "C" void kernel_launch(void* const* d_in, const int* in_sizes, int n_in,
                              void* d_out, int out_size, void* d_ws, size_t ws_size,
                              hipStream_t stream) {
    const float* inputs = (const float*)d_in[0];
    const float* Wk_w   = (const float*)d_in[1];
    const float* Uk_w   = (const float*)d_in[2];
    const float* b_w    = (const float*)d_in[3];
    const float* Wk_d   = (const float*)d_in[4];
    const float* Uk_d   = (const float*)d_in[5];
    const float* b_d    = (const float*)d_in[6];
    const float* Wd     = (const float*)d_in[7];
    const float* bd     = (const float*)d_in[8];
    float* out = (float*)d_out;

    const int B = in_sizes[0] / TSTEPS;
    const int grid = (B + 127) / 128;  // 128 batch rows per 256-thread block
    lstm_feedback_mfma14<<<grid, 256, 0, stream>>>(
        inputs, Wk_w, Uk_w, b_w, Wk_d, Uk_d, b_d, Wd, bd, out, B);
}